// Round 1
// baseline (6516.830 us; speedup 1.0000x reference)
//
#include <hip/hip_runtime.h>

#define N_NODES 100000
#define HID 256
#define N_EDGES 1500000
#define N_REL 3
#define E_PER_REL (N_EDGES / N_REL)

#define BM 64
#define BN 64
#define BK 16

// ---------------------------------------------------------------------------
// h0 = 0.5*(fa @ Wa + fb @ Wb), h0[0,:]=0.   fa:[N,256] fb:[N,384]
// ---------------------------------------------------------------------------
__global__ __launch_bounds__(256) void proj_kernel(
    const float* __restrict__ fa, const float* __restrict__ fb,
    const float* __restrict__ Wa, const float* __restrict__ Wb,
    float* __restrict__ h0)
{
    __shared__ float As[BK][BM + 4];
    __shared__ float Bs[BK][BN];
    const int tid = threadIdx.x;
    const int tx = tid & 15;
    const int ty = tid >> 4;
    const int bm = blockIdx.x * BM;
    const int bn = blockIdx.y * BN;
    float acc[4][4] = {};

    for (int phase = 0; phase < 2; ++phase) {
        const float* __restrict__ A = phase ? fb : fa;
        const float* __restrict__ B = phase ? Wb : Wa;
        const int K = phase ? 384 : 256;
        for (int k0 = 0; k0 < K; k0 += BK) {
            #pragma unroll
            for (int i = 0; i < (BM * BK) / 256; ++i) {
                int idx = tid + i * 256;
                int k = idx & (BK - 1);
                int m = idx >> 4;
                int row = bm + m;
                As[k][m] = (row < N_NODES) ? A[(size_t)row * K + k0 + k] : 0.f;
            }
            #pragma unroll
            for (int i = 0; i < (BK * BN) / 256; ++i) {
                int idx = tid + i * 256;
                int n = idx & (BN - 1);
                int k = idx >> 6;
                Bs[k][n] = B[(size_t)(k0 + k) * HID + bn + n];
            }
            __syncthreads();
            #pragma unroll
            for (int k = 0; k < BK; ++k) {
                const float4 av = *(const float4*)&As[k][ty * 4];
                const float4 bv = *(const float4*)&Bs[k][tx * 4];
                const float a_[4] = {av.x, av.y, av.z, av.w};
                const float b_[4] = {bv.x, bv.y, bv.z, bv.w};
                #pragma unroll
                for (int i = 0; i < 4; ++i)
                    #pragma unroll
                    for (int j = 0; j < 4; ++j)
                        acc[i][j] = fmaf(a_[i], b_[j], acc[i][j]);
            }
            __syncthreads();
        }
    }
    #pragma unroll
    for (int i = 0; i < 4; ++i) {
        int row = bm + ty * 4 + i;
        if (row >= N_NODES) continue;
        #pragma unroll
        for (int j = 0; j < 4; ++j) {
            int col = bn + tx * 4 + j;
            h0[(size_t)row * HID + col] = (row == 0) ? 0.f : 0.5f * acc[i][j];
        }
    }
}

// ---------------------------------------------------------------------------
// Per-edge scatter: S[dst,:] += w * h0[src,:]; den[dst] += w.
// One wave (64 lanes) per edge, float4 gather, 4 f32 atomics per lane.
// ---------------------------------------------------------------------------
__global__ __launch_bounds__(256) void scatter_kernel(
    const float* __restrict__ h0,
    const int* __restrict__ src, const int* __restrict__ dst,
    const float* __restrict__ w,
    float* __restrict__ S, float* __restrict__ den, int nedges)
{
    int wid = (blockIdx.x * 256 + threadIdx.x) >> 6;
    int lane = threadIdx.x & 63;
    if (wid >= nedges) return;
    int s = src[wid];
    int d = dst[wid];
    float wt = w[wid];
    const float4 v = ((const float4*)(h0 + (size_t)s * HID))[lane];
    float* Sp = S + (size_t)d * HID + lane * 4;
    atomicAdd(Sp + 0, wt * v.x);
    atomicAdd(Sp + 1, wt * v.y);
    atomicAdd(Sp + 2, wt * v.z);
    atomicAdd(Sp + 3, wt * v.w);
    if (lane == 0) atomicAdd(&den[d], wt);
}

__global__ __launch_bounds__(256) void invden_kernel(
    const float* __restrict__ den, float* __restrict__ invden)
{
    int i = blockIdx.x * 256 + threadIdx.x;
    if (i < N_NODES) invden[i] = 1.0f / fmaxf(den[i], 1e-8f);
}

// ---------------------------------------------------------------------------
// agg += (S * invden[row]) @ B    (B = Wr[r], [256,256])
// ---------------------------------------------------------------------------
__global__ __launch_bounds__(256) void relgemm_kernel(
    const float* __restrict__ S, const float* __restrict__ B,
    const float* __restrict__ invden, float* __restrict__ agg)
{
    __shared__ float As[BK][BM + 4];
    __shared__ float Bs[BK][BN];
    const int tid = threadIdx.x;
    const int tx = tid & 15;
    const int ty = tid >> 4;
    const int bm = blockIdx.x * BM;
    const int bn = blockIdx.y * BN;
    float acc[4][4] = {};

    for (int k0 = 0; k0 < HID; k0 += BK) {
        #pragma unroll
        for (int i = 0; i < (BM * BK) / 256; ++i) {
            int idx = tid + i * 256;
            int k = idx & (BK - 1);
            int m = idx >> 4;
            int row = bm + m;
            As[k][m] = (row < N_NODES)
                ? S[(size_t)row * HID + k0 + k] * invden[row] : 0.f;
        }
        #pragma unroll
        for (int i = 0; i < (BK * BN) / 256; ++i) {
            int idx = tid + i * 256;
            int n = idx & (BN - 1);
            int k = idx >> 6;
            Bs[k][n] = B[(size_t)(k0 + k) * HID + bn + n];
        }
        __syncthreads();
        #pragma unroll
        for (int k = 0; k < BK; ++k) {
            const float4 av = *(const float4*)&As[k][ty * 4];
            const float4 bv = *(const float4*)&Bs[k][tx * 4];
            const float a_[4] = {av.x, av.y, av.z, av.w};
            const float b_[4] = {bv.x, bv.y, bv.z, bv.w};
            #pragma unroll
            for (int i = 0; i < 4; ++i)
                #pragma unroll
                for (int j = 0; j < 4; ++j)
                    acc[i][j] = fmaf(a_[i], b_[j], acc[i][j]);
        }
        __syncthreads();
    }
    #pragma unroll
    for (int i = 0; i < 4; ++i) {
        int row = bm + ty * 4 + i;
        if (row >= N_NODES) continue;
        #pragma unroll
        for (int j = 0; j < 4; ++j) {
            int col = bn + tx * 4 + j;
            agg[(size_t)row * HID + col] += acc[i][j];
        }
    }
}

// ---------------------------------------------------------------------------
// out = LayerNorm(h0 + agg) * gamma + beta, out[0,:]=0.  One block per row.
// agg aliases out (read-before-write per element, same thread).
// ---------------------------------------------------------------------------
__device__ __forceinline__ float wave_reduce_sum(float v) {
    #pragma unroll
    for (int off = 32; off > 0; off >>= 1)
        v += __shfl_xor(v, off, 64);
    return v;
}

__global__ __launch_bounds__(256) void ln_kernel(
    const float* __restrict__ h0, const float* __restrict__ agg,
    const float* __restrict__ gamma, const float* __restrict__ beta,
    float* __restrict__ out)
{
    const int row = blockIdx.x;
    const int t = threadIdx.x;
    const size_t base = (size_t)row * HID;
    float x = h0[base + t] + agg[base + t];

    __shared__ float red[8];
    float s1 = wave_reduce_sum(x);
    float s2 = wave_reduce_sum(x * x);
    int wv = t >> 6;
    if ((t & 63) == 0) { red[wv] = s1; red[4 + wv] = s2; }
    __syncthreads();
    float tot  = red[0] + red[1] + red[2] + red[3];
    float tot2 = red[4] + red[5] + red[6] + red[7];
    float mean = tot * (1.0f / HID);
    float var  = tot2 * (1.0f / HID) - mean * mean;
    float rs = rsqrtf(var + 1e-5f);
    float y = (x - mean) * rs * gamma[t] + beta[t];
    out[base + t] = (row == 0) ? 0.f : y;
}

// ---------------------------------------------------------------------------
extern "C" void kernel_launch(void* const* d_in, const int* in_sizes, int n_in,
                              void* d_out, int out_size, void* d_ws, size_t ws_size,
                              hipStream_t stream) {
    const float* fa    = (const float*)d_in[0];
    const float* fb    = (const float*)d_in[1];
    const float* Wa    = (const float*)d_in[2];
    const float* Wb    = (const float*)d_in[3];
    const float* Wr    = (const float*)d_in[4];
    const float* gamma = (const float*)d_in[5];
    const float* beta  = (const float*)d_in[6];
    const float* ew    = (const float*)d_in[7];
    const int*   esrc  = (const int*)d_in[8];
    const int*   edst  = (const int*)d_in[9];
    float* out = (float*)d_out;

    const size_t H0B = (size_t)N_NODES * HID * sizeof(float);  // 102.4 MB
    char* ws = (char*)d_ws;
    float* h0     = (float*)(ws);                               // [N,256]
    float* S      = (float*)(ws + H0B);                         // [N,256]
    float* den    = (float*)(ws + 2 * H0B);                     // [N]
    float* invden = den + N_NODES;                              // [N]

    float* agg = out;  // accumulate aggregated messages directly in d_out

    hipMemsetAsync(agg, 0, (size_t)out_size * sizeof(float), stream);

    dim3 ggrid((N_NODES + BM - 1) / BM, HID / BN);
    proj_kernel<<<ggrid, 256, 0, stream>>>(fa, fb, Wa, Wb, h0);

    for (int r = 0; r < N_REL; ++r) {
        hipMemsetAsync(S, 0, H0B, stream);
        hipMemsetAsync(den, 0, N_NODES * sizeof(float), stream);
        scatter_kernel<<<(E_PER_REL * 64) / 256, 256, 0, stream>>>(
            h0, esrc + (size_t)r * E_PER_REL, edst + (size_t)r * E_PER_REL,
            ew + (size_t)r * E_PER_REL, S, den, E_PER_REL);
        invden_kernel<<<(N_NODES + 255) / 256, 256, 0, stream>>>(den, invden);
        relgemm_kernel<<<ggrid, 256, 0, stream>>>(
            S, Wr + (size_t)r * HID * HID, invden, agg);
    }

    ln_kernel<<<N_NODES, 256, 0, stream>>>(h0, agg, gamma, beta, out);
}

// Round 2
// 1717.429 us; speedup vs baseline: 3.7945x; 3.7945x over previous
//
#include <hip/hip_runtime.h>

#define N_NODES 100000
#define HID 256
#define N_EDGES 1500000
#define N_REL 3
#define E_PER_REL (N_EDGES / N_REL)
#define NKEYS (N_REL * N_NODES)

#define BM 64
#define BN 64
#define BK 16

#define SCAN_CHUNK 1024
#define NSCANBLK ((NKEYS + SCAN_CHUNK - 1) / SCAN_CHUNK)   // 293

// ---------------------------------------------------------------------------
// h0 = 0.5*(fa @ Wa + fb @ Wb), h0[0,:]=0.   fa:[N,256] fb:[N,384]
// ---------------------------------------------------------------------------
__global__ __launch_bounds__(256) void proj_kernel(
    const float* __restrict__ fa, const float* __restrict__ fb,
    const float* __restrict__ Wa, const float* __restrict__ Wb,
    float* __restrict__ h0)
{
    __shared__ float As[BK][BM + 4];
    __shared__ float Bs[BK][BN];
    const int tid = threadIdx.x;
    const int tx = tid & 15;
    const int ty = tid >> 4;
    const int bm = blockIdx.x * BM;
    const int bn = blockIdx.y * BN;
    float acc[4][4] = {};

    for (int phase = 0; phase < 2; ++phase) {
        const float* __restrict__ A = phase ? fb : fa;
        const float* __restrict__ B = phase ? Wb : Wa;
        const int K = phase ? 384 : 256;
        for (int k0 = 0; k0 < K; k0 += BK) {
            #pragma unroll
            for (int i = 0; i < (BM * BK) / 256; ++i) {
                int idx = tid + i * 256;
                int k = idx & (BK - 1);
                int m = idx >> 4;
                int row = bm + m;
                As[k][m] = (row < N_NODES) ? A[(size_t)row * K + k0 + k] : 0.f;
            }
            #pragma unroll
            for (int i = 0; i < (BK * BN) / 256; ++i) {
                int idx = tid + i * 256;
                int n = idx & (BN - 1);
                int k = idx >> 6;
                Bs[k][n] = B[(size_t)(k0 + k) * HID + bn + n];
            }
            __syncthreads();
            #pragma unroll
            for (int k = 0; k < BK; ++k) {
                const float4 av = *(const float4*)&As[k][ty * 4];
                const float4 bv = *(const float4*)&Bs[k][tx * 4];
                const float a_[4] = {av.x, av.y, av.z, av.w};
                const float b_[4] = {bv.x, bv.y, bv.z, bv.w};
                #pragma unroll
                for (int i = 0; i < 4; ++i)
                    #pragma unroll
                    for (int j = 0; j < 4; ++j)
                        acc[i][j] = fmaf(a_[i], b_[j], acc[i][j]);
            }
            __syncthreads();
        }
    }
    #pragma unroll
    for (int i = 0; i < 4; ++i) {
        int row = bm + ty * 4 + i;
        if (row >= N_NODES) continue;
        #pragma unroll
        for (int j = 0; j < 4; ++j) {
            int col = bn + tx * 4 + j;
            h0[(size_t)row * HID + col] = (row == 0) ? 0.f : 0.5f * acc[i][j];
        }
    }
}

// ---------------------------------------------------------------------------
// CSR build: histogram -> hierarchical exclusive scan -> bucket fill
// key = r * N_NODES + dst[i]
// ---------------------------------------------------------------------------
__global__ __launch_bounds__(256) void hist_kernel(
    const int* __restrict__ dst, int* __restrict__ count)
{
    int i = blockIdx.x * 256 + threadIdx.x;
    if (i >= N_EDGES) return;
    int r = i / E_PER_REL;
    atomicAdd(&count[r * N_NODES + dst[i]], 1);
}

// per-block exclusive scan of `count` (chunk=1024) -> offset; block totals -> bsum
__global__ __launch_bounds__(256) void scan1_kernel(
    const int* __restrict__ count, int* __restrict__ offset,
    int* __restrict__ bsum)
{
    __shared__ int tmp[256];
    const int t = threadIdx.x;
    const int base = blockIdx.x * SCAN_CHUNK + t * 4;
    int v[4];
    #pragma unroll
    for (int j = 0; j < 4; ++j)
        v[j] = (base + j < NKEYS) ? count[base + j] : 0;
    int tsum = v[0] + v[1] + v[2] + v[3];

    tmp[t] = tsum;
    __syncthreads();
    #pragma unroll
    for (int off = 1; off < 256; off <<= 1) {
        int x = (t >= off) ? tmp[t - off] : 0;
        __syncthreads();
        tmp[t] += x;
        __syncthreads();
    }
    int run = tmp[t] - tsum;   // exclusive prefix of this thread within block
    #pragma unroll
    for (int j = 0; j < 4; ++j) {
        if (base + j < NKEYS) offset[base + j] = run;
        run += v[j];
    }
    if (t == 0) bsum[blockIdx.x] = tmp[255];
}

// single-block exclusive scan of bsum[NSCANBLK] in place (NSCANBLK <= 512)
__global__ __launch_bounds__(256) void scan2_kernel(int* __restrict__ bsum)
{
    __shared__ int tmp[256];
    const int t = threadIdx.x;
    int v0 = (2 * t     < NSCANBLK) ? bsum[2 * t]     : 0;
    int v1 = (2 * t + 1 < NSCANBLK) ? bsum[2 * t + 1] : 0;
    int psum = v0 + v1;
    tmp[t] = psum;
    __syncthreads();
    #pragma unroll
    for (int off = 1; off < 256; off <<= 1) {
        int x = (t >= off) ? tmp[t - off] : 0;
        __syncthreads();
        tmp[t] += x;
        __syncthreads();
    }
    int excl = tmp[t] - psum;
    if (2 * t     < NSCANBLK) bsum[2 * t]     = excl;
    if (2 * t + 1 < NSCANBLK) bsum[2 * t + 1] = excl + v0;
}

// offset[i] += bsum[i/1024]  (completes the global exclusive scan)
__global__ __launch_bounds__(256) void scan3_kernel(
    int* __restrict__ offset, const int* __restrict__ bsum)
{
    int i = blockIdx.x * 256 + threadIdx.x;
    if (i >= NKEYS) return;
    offset[i] += bsum[i / SCAN_CHUNK];
}

// bucket fill: pos = offset[key]++ (atomic); after this, offset[key] == segment END
__global__ __launch_bounds__(256) void fill_kernel(
    const int* __restrict__ src, const int* __restrict__ dst,
    const float* __restrict__ w,
    int* __restrict__ offset, int* __restrict__ csr_src,
    float* __restrict__ csr_w)
{
    int i = blockIdx.x * 256 + threadIdx.x;
    if (i >= N_EDGES) return;
    int r = i / E_PER_REL;
    int key = r * N_NODES + dst[i];
    int pos = atomicAdd(&offset[key], 1);
    csr_src[pos] = src[i];
    csr_w[pos] = w[i];
}

// ---------------------------------------------------------------------------
// Gather-side aggregation: one wave per dst node.
// S[n,:] = (sum_e w_e * h0[src_e,:]) / max(sum_e w_e, 1e-8)
// ends[n] = offset[key] (post-fill) ; start = ends[n] - count[key]
// ---------------------------------------------------------------------------
__global__ __launch_bounds__(256) void gather_kernel(
    const float* __restrict__ h0,
    const int* __restrict__ ends, const int* __restrict__ count,
    const int* __restrict__ csr_src, const float* __restrict__ csr_w,
    float* __restrict__ S)
{
    int wid = (blockIdx.x * 256 + threadIdx.x) >> 6;
    int lane = threadIdx.x & 63;
    if (wid >= N_NODES) return;
    int end = ends[wid];
    int start = end - count[wid];
    float4 acc = make_float4(0.f, 0.f, 0.f, 0.f);
    float den = 0.f;
    for (int p = start; p < end; ++p) {
        int s = csr_src[p];
        float wt = csr_w[p];
        const float4 v = ((const float4*)(h0 + (size_t)s * HID))[lane];
        acc.x = fmaf(wt, v.x, acc.x);
        acc.y = fmaf(wt, v.y, acc.y);
        acc.z = fmaf(wt, v.z, acc.z);
        acc.w = fmaf(wt, v.w, acc.w);
        den += wt;
    }
    float inv = 1.0f / fmaxf(den, 1e-8f);
    acc.x *= inv; acc.y *= inv; acc.z *= inv; acc.w *= inv;
    ((float4*)(S + (size_t)wid * HID))[lane] = acc;
}

// ---------------------------------------------------------------------------
// agg (+)= S @ B    (B = Wr[r], [256,256]); S already den-scaled
// ---------------------------------------------------------------------------
__global__ __launch_bounds__(256) void relgemm_kernel(
    const float* __restrict__ S, const float* __restrict__ B,
    float* __restrict__ agg, int accumulate)
{
    __shared__ float As[BK][BM + 4];
    __shared__ float Bs[BK][BN];
    const int tid = threadIdx.x;
    const int tx = tid & 15;
    const int ty = tid >> 4;
    const int bm = blockIdx.x * BM;
    const int bn = blockIdx.y * BN;
    float acc[4][4] = {};

    for (int k0 = 0; k0 < HID; k0 += BK) {
        #pragma unroll
        for (int i = 0; i < (BM * BK) / 256; ++i) {
            int idx = tid + i * 256;
            int k = idx & (BK - 1);
            int m = idx >> 4;
            int row = bm + m;
            As[k][m] = (row < N_NODES) ? S[(size_t)row * HID + k0 + k] : 0.f;
        }
        #pragma unroll
        for (int i = 0; i < (BK * BN) / 256; ++i) {
            int idx = tid + i * 256;
            int n = idx & (BN - 1);
            int k = idx >> 6;
            Bs[k][n] = B[(size_t)(k0 + k) * HID + bn + n];
        }
        __syncthreads();
        #pragma unroll
        for (int k = 0; k < BK; ++k) {
            const float4 av = *(const float4*)&As[k][ty * 4];
            const float4 bv = *(const float4*)&Bs[k][tx * 4];
            const float a_[4] = {av.x, av.y, av.z, av.w};
            const float b_[4] = {bv.x, bv.y, bv.z, bv.w};
            #pragma unroll
            for (int i = 0; i < 4; ++i)
                #pragma unroll
                for (int j = 0; j < 4; ++j)
                    acc[i][j] = fmaf(a_[i], b_[j], acc[i][j]);
        }
        __syncthreads();
    }
    #pragma unroll
    for (int i = 0; i < 4; ++i) {
        int row = bm + ty * 4 + i;
        if (row >= N_NODES) continue;
        #pragma unroll
        for (int j = 0; j < 4; ++j) {
            int col = bn + tx * 4 + j;
            size_t o = (size_t)row * HID + col;
            agg[o] = accumulate ? (agg[o] + acc[i][j]) : acc[i][j];
        }
    }
}

// ---------------------------------------------------------------------------
// out = LayerNorm(h0 + agg) * gamma + beta, out[0,:]=0.  One block per row.
// ---------------------------------------------------------------------------
__device__ __forceinline__ float wave_reduce_sum(float v) {
    #pragma unroll
    for (int off = 32; off > 0; off >>= 1)
        v += __shfl_xor(v, off, 64);
    return v;
}

__global__ __launch_bounds__(256) void ln_kernel(
    const float* __restrict__ h0, const float* __restrict__ agg,
    const float* __restrict__ gamma, const float* __restrict__ beta,
    float* __restrict__ out)
{
    const int row = blockIdx.x;
    const int t = threadIdx.x;
    const size_t base = (size_t)row * HID;
    float x = h0[base + t] + agg[base + t];

    __shared__ float red[8];
    float s1 = wave_reduce_sum(x);
    float s2 = wave_reduce_sum(x * x);
    int wv = t >> 6;
    if ((t & 63) == 0) { red[wv] = s1; red[4 + wv] = s2; }
    __syncthreads();
    float tot  = red[0] + red[1] + red[2] + red[3];
    float tot2 = red[4] + red[5] + red[6] + red[7];
    float mean = tot * (1.0f / HID);
    float var  = tot2 * (1.0f / HID) - mean * mean;
    float rs = rsqrtf(var + 1e-5f);
    float y = (x - mean) * rs * gamma[t] + beta[t];
    out[base + t] = (row == 0) ? 0.f : y;
}

// ---------------------------------------------------------------------------
extern "C" void kernel_launch(void* const* d_in, const int* in_sizes, int n_in,
                              void* d_out, int out_size, void* d_ws, size_t ws_size,
                              hipStream_t stream) {
    const float* fa    = (const float*)d_in[0];
    const float* fb    = (const float*)d_in[1];
    const float* Wa    = (const float*)d_in[2];
    const float* Wb    = (const float*)d_in[3];
    const float* Wr    = (const float*)d_in[4];
    const float* gamma = (const float*)d_in[5];
    const float* beta  = (const float*)d_in[6];
    const float* ew    = (const float*)d_in[7];
    const int*   esrc  = (const int*)d_in[8];
    const int*   edst  = (const int*)d_in[9];
    float* out = (float*)d_out;

    const size_t H0B = (size_t)N_NODES * HID * sizeof(float);  // 102,400,000 B
    char* ws = (char*)d_ws;
    float* h0      = (float*)(ws);
    float* S       = (float*)(ws + H0B);
    int*   count   = (int*)  (ws + 2 * H0B);
    int*   offset  = (int*)  (ws + 2 * H0B + 1 * (size_t)NKEYS * 4);
    int*   bsum    = (int*)  (ws + 2 * H0B + 2 * (size_t)NKEYS * 4);
    int*   csr_src = (int*)  (ws + 2 * H0B + 2 * (size_t)NKEYS * 4 + 4096);
    float* csr_w   = (float*)(ws + 2 * H0B + 2 * (size_t)NKEYS * 4 + 4096
                                 + (size_t)N_EDGES * 4);
    float* agg = out;

    dim3 ggrid((N_NODES + BM - 1) / BM, HID / BN);
    proj_kernel<<<ggrid, 256, 0, stream>>>(fa, fb, Wa, Wb, h0);

    // CSR build (all relations at once; key = r*N + dst)
    hipMemsetAsync(count, 0, (size_t)NKEYS * 4, stream);
    const int egrid = (N_EDGES + 255) / 256;
    hist_kernel<<<egrid, 256, 0, stream>>>(edst, count);
    scan1_kernel<<<NSCANBLK, 256, 0, stream>>>(count, offset, bsum);
    scan2_kernel<<<1, 256, 0, stream>>>(bsum);
    scan3_kernel<<<(NKEYS + 255) / 256, 256, 0, stream>>>(offset, bsum);
    fill_kernel<<<egrid, 256, 0, stream>>>(esrc, edst, ew, offset, csr_src, csr_w);
    // post-fill: offset[key] == segment end; start = end - count[key]

    for (int r = 0; r < N_REL; ++r) {
        gather_kernel<<<(N_NODES * 64 + 255) / 256, 256, 0, stream>>>(
            h0, offset + (size_t)r * N_NODES, count + (size_t)r * N_NODES,
            csr_src, csr_w, S);
        relgemm_kernel<<<ggrid, 256, 0, stream>>>(
            S, Wr + (size_t)r * HID * HID, agg, r > 0 ? 1 : 0);
    }

    ln_kernel<<<N_NODES, 256, 0, stream>>>(h0, agg, gamma, beta, out);
}

// Round 5
// 801.033 us; speedup vs baseline: 8.1355x; 2.1440x over previous
//
#include <hip/hip_runtime.h>

#define N_NODES 100000
#define HID 256
#define N_EDGES 1500000
#define N_REL 3
#define E_PER_REL (N_EDGES / N_REL)
#define NKEYS (N_REL * N_NODES)
#define KP 640                 // proj K  (256 + 384)
#define KR 768                 // relation K (3 * 256)

#define SCAN_CHUNK 1024
#define NSCANBLK ((NKEYS + SCAN_CHUNK - 1) / SCAN_CHUNK)   // 293

typedef __attribute__((ext_vector_type(8))) short bf16x8;
typedef __attribute__((ext_vector_type(4))) float f32x4;

__device__ __forceinline__ short f2bf(float x) {  // RNE f32 -> bf16
    union { float f; unsigned u; } v; v.f = x;
    unsigned r = v.u + 0x7fffu + ((v.u >> 16) & 1u);
    return (short)(r >> 16);
}
__device__ __forceinline__ float bf2f(short h) {
    union { unsigned u; float f; } v;
    v.u = ((unsigned)(unsigned short)h) << 16;
    return v.f;
}
// slot swizzle: LDS row layout = [row][slot^xorf(row)], slot = 16B unit
__device__ __forceinline__ int xorf(int r) { return (r & 3) ^ ((r >> 2) & 3); }

// ---------------------------------------------------------------------------
// Weight prep: WTp[c][k] = bf16(0.5 * Wp[k][c])  (Wp = [Wa;Wb], k in [0,640))
//              WTr[c][k] = bf16(Wr[k>>8][k&255][c])          (k in [0,768))
// ---------------------------------------------------------------------------
__global__ __launch_bounds__(256) void wprep_kernel(
    const float* __restrict__ Wa, const float* __restrict__ Wb,
    const float* __restrict__ Wr,
    short* __restrict__ WTp, short* __restrict__ WTr)
{
    int idx = blockIdx.x * 256 + threadIdx.x;
    if (idx < 256 * KP) {
        int c = idx / KP, k = idx - c * KP;
        float v = (k < 256) ? Wa[k * HID + c] : Wb[(k - 256) * HID + c];
        WTp[idx] = f2bf(0.5f * v);
    } else {
        int j = idx - 256 * KP;
        if (j < 256 * KR) {
            int c = j / KR, k = j - c * KR;
            WTr[j] = f2bf(Wr[(k >> 8) * HID * HID + (k & 255) * HID + c]);
        }
    }
}

// ---------------------------------------------------------------------------
// proj GEMM: h0h[N,256] (bf16) = bf16( fa@(.5Wa) + fb@(.5Wb) ), row 0 zeroed.
// Tile 128x256, 4 waves (2x2), wave tile 64x128, BK=32.
// Reg-staged LDS: bf16 [rows][4 x 16B slots], slot ^= xorf(row) both sides.
// ---------------------------------------------------------------------------
__global__ __launch_bounds__(256) void proj_gemm(
    const float* __restrict__ fa, const float* __restrict__ fb,
    const short* __restrict__ WTp, short* __restrict__ h0h)
{
    __shared__ short smA[128 * 32];   // 8 KB
    __shared__ short smB[256 * 32];   // 16 KB
    const int tid = threadIdx.x;
    const int lane = tid & 63;
    const int w = tid >> 6;
    const int wr = w >> 1, wc = w & 1;
    const int brow = blockIdx.x * 128;

    f32x4 acc[4][8] = {};

    // A staging role: thread t covers (row = t>>1, k-half = t&1) -> 16 floats
    const int arow = tid >> 1;
    const int ahalf = tid & 1;
    int garow = brow + arow;
    if (garow >= N_NODES) garow = N_NODES - 1;
    const int as0 = (ahalf * 2 + 0) ^ xorf(arow);
    const int as1 = (ahalf * 2 + 1) ^ xorf(arow);
    // B staging role: thread t covers col = t -> 32 bf16
    const int bxor = xorf(tid);

    for (int k0 = 0; k0 < KP; k0 += 32) {
        // ---- stage A (fp32 -> bf16 in regs -> ds_write_b128) ----
        const float* asrc; int astr, kk;
        if (k0 < 256) { asrc = fa; astr = 256; kk = k0; }
        else          { asrc = fb; astr = 384; kk = k0 - 256; }
        const float* ap = asrc + (size_t)garow * astr + kk + ahalf * 16;
        f32x4 v0 = *(const f32x4*)(ap + 0);
        f32x4 v1 = *(const f32x4*)(ap + 4);
        f32x4 v2 = *(const f32x4*)(ap + 8);
        f32x4 v3 = *(const f32x4*)(ap + 12);
        bf16x8 ha, hb;
        ha[0] = f2bf(v0.x); ha[1] = f2bf(v0.y); ha[2] = f2bf(v0.z); ha[3] = f2bf(v0.w);
        ha[4] = f2bf(v1.x); ha[5] = f2bf(v1.y); ha[6] = f2bf(v1.z); ha[7] = f2bf(v1.w);
        hb[0] = f2bf(v2.x); hb[1] = f2bf(v2.y); hb[2] = f2bf(v2.z); hb[3] = f2bf(v2.w);
        hb[4] = f2bf(v3.x); hb[5] = f2bf(v3.y); hb[6] = f2bf(v3.z); hb[7] = f2bf(v3.w);
        // ---- stage B ----
        const short* bp = WTp + (size_t)tid * KP + k0;
        bf16x8 bv0 = *(const bf16x8*)(bp + 0);
        bf16x8 bv1 = *(const bf16x8*)(bp + 8);
        bf16x8 bv2 = *(const bf16x8*)(bp + 16);
        bf16x8 bv3 = *(const bf16x8*)(bp + 24);

        __syncthreads();   // previous iteration's reads complete
        *(bf16x8*)((char*)smA + arow * 64 + as0 * 16) = ha;
        *(bf16x8*)((char*)smA + arow * 64 + as1 * 16) = hb;
        *(bf16x8*)((char*)smB + tid * 64 + ((0 ^ bxor)) * 16) = bv0;
        *(bf16x8*)((char*)smB + tid * 64 + ((1 ^ bxor)) * 16) = bv1;
        *(bf16x8*)((char*)smB + tid * 64 + ((2 ^ bxor)) * 16) = bv2;
        *(bf16x8*)((char*)smB + tid * 64 + ((3 ^ bxor)) * 16) = bv3;
        __syncthreads();

        bf16x8 afr[4], bfr[8];
        #pragma unroll
        for (int m = 0; m < 4; ++m) {
            int rt = wr * 64 + m * 16 + (lane & 15);
            int s = (lane >> 4) ^ xorf(rt);
            afr[m] = *(const bf16x8*)((const char*)smA + rt * 64 + s * 16);
        }
        #pragma unroll
        for (int n = 0; n < 8; ++n) {
            int ct = wc * 128 + n * 16 + (lane & 15);
            int s = (lane >> 4) ^ xorf(ct);
            bfr[n] = *(const bf16x8*)((const char*)smB + ct * 64 + s * 16);
        }
        #pragma unroll
        for (int m = 0; m < 4; ++m)
            #pragma unroll
            for (int n = 0; n < 8; ++n)
                acc[m][n] = __builtin_amdgcn_mfma_f32_16x16x32_bf16(
                    afr[m], bfr[n], acc[m][n], 0, 0, 0);
    }

    #pragma unroll
    for (int m = 0; m < 4; ++m) {
        #pragma unroll
        for (int j = 0; j < 4; ++j) {
            int row = brow + wr * 64 + m * 16 + ((lane >> 4) << 2) + j;
            if (row >= N_NODES) continue;
            #pragma unroll
            for (int n = 0; n < 8; ++n) {
                int col = wc * 128 + n * 16 + (lane & 15);
                short v = (row == 0) ? (short)0 : f2bf(acc[m][n][j]);
                h0h[(size_t)row * HID + col] = v;
            }
        }
    }
}

// ---------------------------------------------------------------------------
// rel GEMM: agg[N,256] (f32) = S[N,768](bf16) @ WTr^T  (WTr [256][768] bf16)
// ---------------------------------------------------------------------------
__global__ __launch_bounds__(256) void rel_gemm(
    const short* __restrict__ S, const short* __restrict__ WTr,
    float* __restrict__ agg)
{
    __shared__ short smA[128 * 32];
    __shared__ short smB[256 * 32];
    const int tid = threadIdx.x;
    const int lane = tid & 63;
    const int w = tid >> 6;
    const int wr = w >> 1, wc = w & 1;
    const int brow = blockIdx.x * 128;

    f32x4 acc[4][8] = {};

    const int arow = tid >> 1;
    const int ahalf = tid & 1;
    int garow = brow + arow;
    if (garow >= N_NODES) garow = N_NODES - 1;
    const int as0 = (ahalf * 2 + 0) ^ xorf(arow);
    const int as1 = (ahalf * 2 + 1) ^ xorf(arow);
    const int bxor = xorf(tid);

    for (int k0 = 0; k0 < KR; k0 += 32) {
        const short* ap = S + (size_t)garow * KR + k0 + ahalf * 16;
        bf16x8 ha = *(const bf16x8*)(ap + 0);
        bf16x8 hb = *(const bf16x8*)(ap + 8);
        const short* bp = WTr + (size_t)tid * KR + k0;
        bf16x8 bv0 = *(const bf16x8*)(bp + 0);
        bf16x8 bv1 = *(const bf16x8*)(bp + 8);
        bf16x8 bv2 = *(const bf16x8*)(bp + 16);
        bf16x8 bv3 = *(const bf16x8*)(bp + 24);

        __syncthreads();
        *(bf16x8*)((char*)smA + arow * 64 + as0 * 16) = ha;
        *(bf16x8*)((char*)smA + arow * 64 + as1 * 16) = hb;
        *(bf16x8*)((char*)smB + tid * 64 + ((0 ^ bxor)) * 16) = bv0;
        *(bf16x8*)((char*)smB + tid * 64 + ((1 ^ bxor)) * 16) = bv1;
        *(bf16x8*)((char*)smB + tid * 64 + ((2 ^ bxor)) * 16) = bv2;
        *(bf16x8*)((char*)smB + tid * 64 + ((3 ^ bxor)) * 16) = bv3;
        __syncthreads();

        bf16x8 afr[4], bfr[8];
        #pragma unroll
        for (int m = 0; m < 4; ++m) {
            int rt = wr * 64 + m * 16 + (lane & 15);
            int s = (lane >> 4) ^ xorf(rt);
            afr[m] = *(const bf16x8*)((const char*)smA + rt * 64 + s * 16);
        }
        #pragma unroll
        for (int n = 0; n < 8; ++n) {
            int ct = wc * 128 + n * 16 + (lane & 15);
            int s = (lane >> 4) ^ xorf(ct);
            bfr[n] = *(const bf16x8*)((const char*)smB + ct * 64 + s * 16);
        }
        #pragma unroll
        for (int m = 0; m < 4; ++m)
            #pragma unroll
            for (int n = 0; n < 8; ++n)
                acc[m][n] = __builtin_amdgcn_mfma_f32_16x16x32_bf16(
                    afr[m], bfr[n], acc[m][n], 0, 0, 0);
    }

    #pragma unroll
    for (int m = 0; m < 4; ++m) {
        #pragma unroll
        for (int j = 0; j < 4; ++j) {
            int row = brow + wr * 64 + m * 16 + ((lane >> 4) << 2) + j;
            if (row >= N_NODES) continue;
            #pragma unroll
            for (int n = 0; n < 8; ++n) {
                int col = wc * 128 + n * 16 + (lane & 15);
                agg[(size_t)row * HID + col] = acc[m][n][j];
            }
        }
    }
}

// ---------------------------------------------------------------------------
// CSR build: histogram -> hierarchical exclusive scan -> bucket fill
// ---------------------------------------------------------------------------
__global__ __launch_bounds__(256) void hist_kernel(
    const int* __restrict__ dst, int* __restrict__ count)
{
    int i = blockIdx.x * 256 + threadIdx.x;
    if (i >= N_EDGES) return;
    int r = i / E_PER_REL;
    atomicAdd(&count[r * N_NODES + dst[i]], 1);
}

__global__ __launch_bounds__(256) void scan1_kernel(
    const int* __restrict__ count, int* __restrict__ offset,
    int* __restrict__ bsum)
{
    __shared__ int tmp[256];
    const int t = threadIdx.x;
    const int base = blockIdx.x * SCAN_CHUNK + t * 4;
    int v[4];
    #pragma unroll
    for (int j = 0; j < 4; ++j)
        v[j] = (base + j < NKEYS) ? count[base + j] : 0;
    int tsum = v[0] + v[1] + v[2] + v[3];
    tmp[t] = tsum;
    __syncthreads();
    #pragma unroll
    for (int off = 1; off < 256; off <<= 1) {
        int x = (t >= off) ? tmp[t - off] : 0;
        __syncthreads();
        tmp[t] += x;
        __syncthreads();
    }
    int run = tmp[t] - tsum;
    #pragma unroll
    for (int j = 0; j < 4; ++j) {
        if (base + j < NKEYS) offset[base + j] = run;
        run += v[j];
    }
    if (t == 0) bsum[blockIdx.x] = tmp[255];
}

__global__ __launch_bounds__(256) void scan2_kernel(int* __restrict__ bsum)
{
    __shared__ int tmp[256];
    const int t = threadIdx.x;
    int v0 = (2 * t     < NSCANBLK) ? bsum[2 * t]     : 0;
    int v1 = (2 * t + 1 < NSCANBLK) ? bsum[2 * t + 1] : 0;
    int psum = v0 + v1;
    tmp[t] = psum;
    __syncthreads();
    #pragma unroll
    for (int off = 1; off < 256; off <<= 1) {
        int x = (t >= off) ? tmp[t - off] : 0;
        __syncthreads();
        tmp[t] += x;
        __syncthreads();
    }
    int excl = tmp[t] - psum;
    if (2 * t     < NSCANBLK) bsum[2 * t]     = excl;
    if (2 * t + 1 < NSCANBLK) bsum[2 * t + 1] = excl + v0;
}

__global__ __launch_bounds__(256) void scan3_kernel(
    int* __restrict__ offset, const int* __restrict__ bsum)
{
    int i = blockIdx.x * 256 + threadIdx.x;
    if (i >= NKEYS) return;
    offset[i] += bsum[i / SCAN_CHUNK];
}

__global__ __launch_bounds__(256) void fill_kernel(
    const int* __restrict__ src, const int* __restrict__ dst,
    const float* __restrict__ w,
    int* __restrict__ offset, int* __restrict__ csr_src,
    float* __restrict__ csr_w)
{
    int i = blockIdx.x * 256 + threadIdx.x;
    if (i >= N_EDGES) return;
    int r = i / E_PER_REL;
    int key = r * N_NODES + dst[i];
    int pos = atomicAdd(&offset[key], 1);
    csr_src[pos] = src[i];
    csr_w[pos] = w[i];
}

// ---------------------------------------------------------------------------
// Gather: one wave per (relation, node). S[node, r*256:(r+1)*256] (bf16) =
//   (sum_e w_e * h0h[src_e,:]) / max(sum_e w_e, 1e-8)
// 64 lanes x 4 bf16 (8 B) = 512 B = exactly one 256-bf16 row.
// ---------------------------------------------------------------------------
__global__ __launch_bounds__(256) void gather_kernel(
    const short* __restrict__ h0h,
    const int* __restrict__ ends, const int* __restrict__ count,
    const int* __restrict__ csr_src, const float* __restrict__ csr_w,
    short* __restrict__ S)
{
    int gw = (blockIdx.x * 256 + threadIdx.x) >> 6;
    int lane = threadIdx.x & 63;
    if (gw >= N_REL * N_NODES) return;
    int r = gw / N_NODES;
    int node = gw - r * N_NODES;
    int end = ends[gw];
    int start = end - count[gw];
    float a0 = 0.f, a1 = 0.f, a2 = 0.f, a3 = 0.f;
    float den = 0.f;
    for (int p = start; p < end; ++p) {
        int s = csr_src[p];
        float wt = csr_w[p];
        short4 v = *(const short4*)(h0h + (size_t)s * HID + lane * 4);
        a0 = fmaf(wt, bf2f(v.x), a0);
        a1 = fmaf(wt, bf2f(v.y), a1);
        a2 = fmaf(wt, bf2f(v.z), a2);
        a3 = fmaf(wt, bf2f(v.w), a3);
        den += wt;
    }
    float inv = 1.0f / fmaxf(den, 1e-8f);
    short4 o;
    o.x = f2bf(a0 * inv);
    o.y = f2bf(a1 * inv);
    o.z = f2bf(a2 * inv);
    o.w = f2bf(a3 * inv);
    *(short4*)(S + (size_t)node * KR + r * HID + lane * 4) = o;
}

// ---------------------------------------------------------------------------
// out = LayerNorm(h0h + agg) * gamma + beta; out[0,:]=0. One block per row.
// agg aliases out (per-element read-then-write by the same thread).
// ---------------------------------------------------------------------------
__device__ __forceinline__ float wave_reduce_sum(float v) {
    #pragma unroll
    for (int off = 32; off > 0; off >>= 1)
        v += __shfl_xor(v, off, 64);
    return v;
}

__global__ __launch_bounds__(256) void ln_kernel(
    const short* __restrict__ h0h, const float* __restrict__ agg,
    const float* __restrict__ gamma, const float* __restrict__ beta,
    float* __restrict__ out)
{
    const int row = blockIdx.x;
    const int t = threadIdx.x;
    const size_t base = (size_t)row * HID;
    float x = bf2f(h0h[base + t]) + agg[base + t];

    __shared__ float red[8];
    float s1 = wave_reduce_sum(x);
    float s2 = wave_reduce_sum(x * x);
    int wv = t >> 6;
    if ((t & 63) == 0) { red[wv] = s1; red[4 + wv] = s2; }
    __syncthreads();
    float tot  = red[0] + red[1] + red[2] + red[3];
    float tot2 = red[4] + red[5] + red[6] + red[7];
    float mean = tot * (1.0f / HID);
    float var  = tot2 * (1.0f / HID) - mean * mean;
    float rs = rsqrtf(var + 1e-5f);
    float y = (x - mean) * rs * gamma[t] + beta[t];
    out[base + t] = (row == 0) ? 0.f : y;
}

// ---------------------------------------------------------------------------
extern "C" void kernel_launch(void* const* d_in, const int* in_sizes, int n_in,
                              void* d_out, int out_size, void* d_ws, size_t ws_size,
                              hipStream_t stream) {
    const float* fa    = (const float*)d_in[0];
    const float* fb    = (const float*)d_in[1];
    const float* Wa    = (const float*)d_in[2];
    const float* Wb    = (const float*)d_in[3];
    const float* Wr    = (const float*)d_in[4];
    const float* gamma = (const float*)d_in[5];
    const float* beta  = (const float*)d_in[6];
    const float* ew    = (const float*)d_in[7];
    const int*   esrc  = (const int*)d_in[8];
    const int*   edst  = (const int*)d_in[9];
    float* out = (float*)d_out;

    char* ws = (char*)d_ws;
    size_t off = 0;
    short* h0h     = (short*)(ws + off); off += (size_t)N_NODES * HID * 2;   // 51.2 MB
    short* S       = (short*)(ws + off); off += (size_t)N_NODES * KR * 2;    // 153.6 MB
    short* WTp     = (short*)(ws + off); off += (size_t)256 * KP * 2;
    short* WTr     = (short*)(ws + off); off += (size_t)256 * KR * 2;
    int*   count   = (int*)  (ws + off); off += (size_t)NKEYS * 4;
    int*   offs    = (int*)  (ws + off); off += (size_t)NKEYS * 4;
    int*   bsum    = (int*)  (ws + off); off += 4096;
    int*   csr_src = (int*)  (ws + off); off += (size_t)N_EDGES * 4;
    float* csr_w   = (float*)(ws + off); off += (size_t)N_EDGES * 4;

    float* agg = out;

    wprep_kernel<<<(256 * KP + 256 * KR) / 256, 256, 0, stream>>>(
        Wa, Wb, Wr, WTp, WTr);

    const int ngrid = (N_NODES + 127) / 128;   // 782
    proj_gemm<<<ngrid, 256, 0, stream>>>(fa, fb, WTp, h0h);

    // CSR build
    hipMemsetAsync(count, 0, (size_t)NKEYS * 4, stream);
    const int egrid = (N_EDGES + 255) / 256;
    hist_kernel<<<egrid, 256, 0, stream>>>(edst, count);
    scan1_kernel<<<NSCANBLK, 256, 0, stream>>>(count, offs, bsum);
    scan2_kernel<<<1, 256, 0, stream>>>(bsum);
    scan3_kernel<<<(NKEYS + 255) / 256, 256, 0, stream>>>(offs, bsum);
    fill_kernel<<<egrid, 256, 0, stream>>>(esrc, edst, ew, offs, csr_src, csr_w);

    gather_kernel<<<(N_REL * N_NODES * 64) / 256, 256, 0, stream>>>(
        h0h, offs, count, csr_src, csr_w, S);

    rel_gemm<<<ngrid, 256, 0, stream>>>(S, WTr, agg);

    ln_kernel<<<N_NODES, 256, 0, stream>>>(h0h, agg, gamma, beta, out);
}

// Round 6
// 597.207 us; speedup vs baseline: 10.9122x; 1.3413x over previous
//
#include <hip/hip_runtime.h>

#define N_NODES 100000
#define HID 256
#define N_EDGES 1500000
#define N_REL 3
#define E_PER_REL (N_EDGES / N_REL)
#define NKEYS (N_REL * N_NODES)
#define KP 640                 // proj K  (256 + 384)
#define KR 768                 // relation K (3 * 256)

#define SCAN_CHUNK 1024
#define NSCANBLK ((NKEYS + SCAN_CHUNK - 1) / SCAN_CHUNK)   // 293

typedef __attribute__((ext_vector_type(8))) short bf16x8;
typedef __attribute__((ext_vector_type(4))) float f32x4;

__device__ __forceinline__ short f2bf(float x) {  // RNE f32 -> bf16
    union { float f; unsigned u; } v; v.f = x;
    unsigned r = v.u + 0x7fffu + ((v.u >> 16) & 1u);
    return (short)(r >> 16);
}
__device__ __forceinline__ float bf2f(short h) {
    union { unsigned u; float f; } v;
    v.u = ((unsigned)(unsigned short)h) << 16;
    return v.f;
}
// slot swizzle: LDS row layout = [row][slot^xorf(row)], slot = 16B unit
__device__ __forceinline__ int xorf(int r) { return (r & 3) ^ ((r >> 2) & 3); }

// ---------------------------------------------------------------------------
// Weight prep: WTp[c][k] = bf16(0.5 * Wp[k][c])  (Wp = [Wa;Wb], k in [0,640))
//              WTr[c][k] = bf16(Wr[k>>8][k&255][c])          (k in [0,768))
// ---------------------------------------------------------------------------
__global__ __launch_bounds__(256) void wprep_kernel(
    const float* __restrict__ Wa, const float* __restrict__ Wb,
    const float* __restrict__ Wr,
    short* __restrict__ WTp, short* __restrict__ WTr)
{
    int idx = blockIdx.x * 256 + threadIdx.x;
    if (idx < 256 * KP) {
        int c = idx / KP, k = idx - c * KP;
        float v = (k < 256) ? Wa[k * HID + c] : Wb[(k - 256) * HID + c];
        WTp[idx] = f2bf(0.5f * v);
    } else {
        int j = idx - 256 * KP;
        if (j < 256 * KR) {
            int c = j / KR, k = j - c * KR;
            WTr[j] = f2bf(Wr[(k >> 8) * HID * HID + (k & 255) * HID + c]);
        }
    }
}

// ---------------------------------------------------------------------------
// proj GEMM: h0h[N,256] (bf16) = bf16( fa@(.5Wa) + fb@(.5Wb) ), row 0 zeroed.
// 512 threads, 8 waves (2 x 4), tile 128x256, wave tile 64x64, BK=32.
// Reg-staged + software-pipelined (prefetch k+1 issued before MFMA of k).
// ---------------------------------------------------------------------------
__global__ __launch_bounds__(512, 4) void proj_gemm(
    const float* __restrict__ fa, const float* __restrict__ fb,
    const short* __restrict__ WTp, short* __restrict__ h0h)
{
    __shared__ short smA[128 * 32];   // 8 KB
    __shared__ short smB[256 * 32];   // 16 KB
    const int tid = threadIdx.x;
    const int lane = tid & 63;
    const int w = tid >> 6;
    const int wr = w >> 2, wc = w & 3;
    const int brow = blockIdx.x * 128;

    f32x4 acc[4][4] = {};

    // A staging: thread t covers (row = t>>2, k-quad = t&3) -> 8 floats
    const int arow = tid >> 2;
    const int akq = tid & 3;
    int garow = brow + arow;
    if (garow >= N_NODES) garow = N_NODES - 1;
    const int aslot = akq ^ xorf(arow);
    // B staging: thread t covers (col = t>>1, k-half = t&1) -> 16 bf16
    const int bcol = tid >> 1;
    const int bkh = tid & 1;
    const int bs0 = (2 * bkh + 0) ^ xorf(bcol);
    const int bs1 = (2 * bkh + 1) ^ xorf(bcol);

    f32x4 pa0, pa1;
    bf16x8 pb0, pb1;
    auto loadA = [&](int k0) {
        const float* asrc; int astr, kk;
        if (k0 < 256) { asrc = fa; astr = 256; kk = k0; }
        else          { asrc = fb; astr = 384; kk = k0 - 256; }
        const float* ap = asrc + (size_t)garow * astr + kk + akq * 8;
        pa0 = *(const f32x4*)(ap + 0);
        pa1 = *(const f32x4*)(ap + 4);
    };
    auto loadB = [&](int k0) {
        const short* bp = WTp + (size_t)bcol * KP + k0 + bkh * 16;
        pb0 = *(const bf16x8*)(bp + 0);
        pb1 = *(const bf16x8*)(bp + 8);
    };

    loadA(0); loadB(0);
    for (int k0 = 0; k0 < KP; k0 += 32) {
        __syncthreads();   // previous iteration's LDS reads complete
        bf16x8 ha;
        ha[0] = f2bf(pa0.x); ha[1] = f2bf(pa0.y); ha[2] = f2bf(pa0.z); ha[3] = f2bf(pa0.w);
        ha[4] = f2bf(pa1.x); ha[5] = f2bf(pa1.y); ha[6] = f2bf(pa1.z); ha[7] = f2bf(pa1.w);
        *(bf16x8*)((char*)smA + arow * 64 + aslot * 16) = ha;
        *(bf16x8*)((char*)smB + bcol * 64 + bs0 * 16) = pb0;
        *(bf16x8*)((char*)smB + bcol * 64 + bs1 * 16) = pb1;
        __syncthreads();
        if (k0 + 32 < KP) { loadA(k0 + 32); loadB(k0 + 32); }  // prefetch

        bf16x8 afr[4], bfr[4];
        #pragma unroll
        for (int m = 0; m < 4; ++m) {
            int rt = wr * 64 + m * 16 + (lane & 15);
            int s = (lane >> 4) ^ xorf(rt);
            afr[m] = *(const bf16x8*)((const char*)smA + rt * 64 + s * 16);
        }
        #pragma unroll
        for (int n = 0; n < 4; ++n) {
            int ct = wc * 64 + n * 16 + (lane & 15);
            int s = (lane >> 4) ^ xorf(ct);
            bfr[n] = *(const bf16x8*)((const char*)smB + ct * 64 + s * 16);
        }
        #pragma unroll
        for (int m = 0; m < 4; ++m)
            #pragma unroll
            for (int n = 0; n < 4; ++n)
                acc[m][n] = __builtin_amdgcn_mfma_f32_16x16x32_bf16(
                    afr[m], bfr[n], acc[m][n], 0, 0, 0);
    }

    #pragma unroll
    for (int m = 0; m < 4; ++m) {
        #pragma unroll
        for (int j = 0; j < 4; ++j) {
            int row = brow + wr * 64 + m * 16 + ((lane >> 4) << 2) + j;
            if (row >= N_NODES) continue;
            #pragma unroll
            for (int n = 0; n < 4; ++n) {
                int col = wc * 64 + n * 16 + (lane & 15);
                short v = (row == 0) ? (short)0 : f2bf(acc[m][n][j]);
                h0h[(size_t)row * HID + col] = v;
            }
        }
    }
}

// ---------------------------------------------------------------------------
// rel GEMM + fused residual LayerNorm:
//   out[N,256] (f32) = LN( h0h + S@WTr^T ) * gamma + beta, row 0 zeroed.
// Same 8-wave pipelined structure; tile covers full 256-col rows -> LN in
// epilogue via 16-lane shfl partials + LDS cross-wave reduction.
// ---------------------------------------------------------------------------
__global__ __launch_bounds__(512, 4) void rel_gemm_ln(
    const short* __restrict__ S, const short* __restrict__ WTr,
    const short* __restrict__ h0h,
    const float* __restrict__ gamma, const float* __restrict__ beta,
    float* __restrict__ out)
{
    __shared__ short smA[128 * 32];     // 8 KB
    __shared__ short smB[256 * 32];     // 16 KB
    __shared__ float redS[128][4];      // 2 KB
    __shared__ float redS2[128][4];     // 2 KB
    __shared__ float smMean[128], smRs[128];   // 1 KB
    __shared__ float smG[256], smBt[256];      // 2 KB
    const int tid = threadIdx.x;
    const int lane = tid & 63;
    const int w = tid >> 6;
    const int wr = w >> 2, wc = w & 3;
    const int brow = blockIdx.x * 128;

    if (tid < 256) { smG[tid] = gamma[tid]; smBt[tid] = beta[tid]; }

    f32x4 acc[4][4] = {};

    const int arow = tid >> 2;
    const int akq = tid & 3;
    int garow = brow + arow;
    if (garow >= N_NODES) garow = N_NODES - 1;
    const int aslot = akq ^ xorf(arow);
    const int bcol = tid >> 1;
    const int bkh = tid & 1;
    const int bs0 = (2 * bkh + 0) ^ xorf(bcol);
    const int bs1 = (2 * bkh + 1) ^ xorf(bcol);

    bf16x8 pa, pb0, pb1;
    auto loadA = [&](int k0) {
        pa = *(const bf16x8*)(S + (size_t)garow * KR + k0 + akq * 8);
    };
    auto loadB = [&](int k0) {
        const short* bp = WTr + (size_t)bcol * KR + k0 + bkh * 16;
        pb0 = *(const bf16x8*)(bp + 0);
        pb1 = *(const bf16x8*)(bp + 8);
    };

    loadA(0); loadB(0);
    for (int k0 = 0; k0 < KR; k0 += 32) {
        __syncthreads();
        *(bf16x8*)((char*)smA + arow * 64 + aslot * 16) = pa;
        *(bf16x8*)((char*)smB + bcol * 64 + bs0 * 16) = pb0;
        *(bf16x8*)((char*)smB + bcol * 64 + bs1 * 16) = pb1;
        __syncthreads();
        if (k0 + 32 < KR) { loadA(k0 + 32); loadB(k0 + 32); }

        bf16x8 afr[4], bfr[4];
        #pragma unroll
        for (int m = 0; m < 4; ++m) {
            int rt = wr * 64 + m * 16 + (lane & 15);
            int s = (lane >> 4) ^ xorf(rt);
            afr[m] = *(const bf16x8*)((const char*)smA + rt * 64 + s * 16);
        }
        #pragma unroll
        for (int n = 0; n < 4; ++n) {
            int ct = wc * 64 + n * 16 + (lane & 15);
            int s = (lane >> 4) ^ xorf(ct);
            bfr[n] = *(const bf16x8*)((const char*)smB + ct * 64 + s * 16);
        }
        #pragma unroll
        for (int m = 0; m < 4; ++m)
            #pragma unroll
            for (int n = 0; n < 4; ++n)
                acc[m][n] = __builtin_amdgcn_mfma_f32_16x16x32_bf16(
                    afr[m], bfr[n], acc[m][n], 0, 0, 0);
    }

    // ---- epilogue: x = acc + h0 ; per-row mean/var ; LN ; write out ----
    #pragma unroll
    for (int m = 0; m < 4; ++m) {
        #pragma unroll
        for (int j = 0; j < 4; ++j) {
            int lrow = wr * 64 + m * 16 + ((lane >> 4) << 2) + j;
            int grow = brow + lrow;
            int crow = (grow < N_NODES) ? grow : 0;
            float s = 0.f, s2 = 0.f;
            #pragma unroll
            for (int n = 0; n < 4; ++n) {
                int col = wc * 64 + n * 16 + (lane & 15);
                float x = acc[m][n][j] + bf2f(h0h[(size_t)crow * HID + col]);
                acc[m][n][j] = x;
                s += x; s2 = fmaf(x, x, s2);
            }
            #pragma unroll
            for (int off = 1; off < 16; off <<= 1) {
                s += __shfl_xor(s, off, 64);
                s2 += __shfl_xor(s2, off, 64);
            }
            if ((lane & 15) == 0) { redS[lrow][wc] = s; redS2[lrow][wc] = s2; }
        }
    }
    __syncthreads();
    if (tid < 128) {
        float tot  = redS[tid][0] + redS[tid][1] + redS[tid][2] + redS[tid][3];
        float tot2 = redS2[tid][0] + redS2[tid][1] + redS2[tid][2] + redS2[tid][3];
        float mean = tot * (1.0f / HID);
        float var = tot2 * (1.0f / HID) - mean * mean;
        smMean[tid] = mean;
        smRs[tid] = rsqrtf(var + 1e-5f);
    }
    __syncthreads();
    #pragma unroll
    for (int m = 0; m < 4; ++m) {
        #pragma unroll
        for (int j = 0; j < 4; ++j) {
            int lrow = wr * 64 + m * 16 + ((lane >> 4) << 2) + j;
            int grow = brow + lrow;
            if (grow >= N_NODES) continue;
            float mean = smMean[lrow], rs = smRs[lrow];
            #pragma unroll
            for (int n = 0; n < 4; ++n) {
                int col = wc * 64 + n * 16 + (lane & 15);
                float y = (acc[m][n][j] - mean) * rs * smG[col] + smBt[col];
                out[(size_t)grow * HID + col] = (grow == 0) ? 0.f : y;
            }
        }
    }
}

// ---------------------------------------------------------------------------
// CSR build: histogram -> hierarchical exclusive scan -> bucket fill
// ---------------------------------------------------------------------------
__global__ __launch_bounds__(256) void hist_kernel(
    const int* __restrict__ dst, int* __restrict__ count)
{
    int i = blockIdx.x * 256 + threadIdx.x;
    if (i >= N_EDGES) return;
    int r = i / E_PER_REL;
    atomicAdd(&count[r * N_NODES + dst[i]], 1);
}

__global__ __launch_bounds__(256) void scan1_kernel(
    const int* __restrict__ count, int* __restrict__ offset,
    int* __restrict__ bsum)
{
    __shared__ int tmp[256];
    const int t = threadIdx.x;
    const int base = blockIdx.x * SCAN_CHUNK + t * 4;
    int v[4];
    #pragma unroll
    for (int j = 0; j < 4; ++j)
        v[j] = (base + j < NKEYS) ? count[base + j] : 0;
    int tsum = v[0] + v[1] + v[2] + v[3];
    tmp[t] = tsum;
    __syncthreads();
    #pragma unroll
    for (int off = 1; off < 256; off <<= 1) {
        int x = (t >= off) ? tmp[t - off] : 0;
        __syncthreads();
        tmp[t] += x;
        __syncthreads();
    }
    int run = tmp[t] - tsum;
    #pragma unroll
    for (int j = 0; j < 4; ++j) {
        if (base + j < NKEYS) offset[base + j] = run;
        run += v[j];
    }
    if (t == 0) bsum[blockIdx.x] = tmp[255];
}

__global__ __launch_bounds__(256) void scan2_kernel(int* __restrict__ bsum)
{
    __shared__ int tmp[256];
    const int t = threadIdx.x;
    int v0 = (2 * t     < NSCANBLK) ? bsum[2 * t]     : 0;
    int v1 = (2 * t + 1 < NSCANBLK) ? bsum[2 * t + 1] : 0;
    int psum = v0 + v1;
    tmp[t] = psum;
    __syncthreads();
    #pragma unroll
    for (int off = 1; off < 256; off <<= 1) {
        int x = (t >= off) ? tmp[t - off] : 0;
        __syncthreads();
        tmp[t] += x;
        __syncthreads();
    }
    int excl = tmp[t] - psum;
    if (2 * t     < NSCANBLK) bsum[2 * t]     = excl;
    if (2 * t + 1 < NSCANBLK) bsum[2 * t + 1] = excl + v0;
}

__global__ __launch_bounds__(256) void scan3_kernel(
    int* __restrict__ offset, const int* __restrict__ bsum)
{
    int i = blockIdx.x * 256 + threadIdx.x;
    if (i >= NKEYS) return;
    offset[i] += bsum[i / SCAN_CHUNK];
}

__global__ __launch_bounds__(256) void fill_kernel(
    const int* __restrict__ src, const int* __restrict__ dst,
    const float* __restrict__ w,
    int* __restrict__ offset, int* __restrict__ csr_src,
    float* __restrict__ csr_w)
{
    int i = blockIdx.x * 256 + threadIdx.x;
    if (i >= N_EDGES) return;
    int r = i / E_PER_REL;
    int key = r * N_NODES + dst[i];
    int pos = atomicAdd(&offset[key], 1);
    csr_src[pos] = src[i];
    csr_w[pos] = w[i];
}

// ---------------------------------------------------------------------------
// Gather: one wave per (relation, node). S[node, r*256:(r+1)*256] (bf16) =
//   (sum_e w_e * h0h[src_e,:]) / max(sum_e w_e, 1e-8)
// 64 lanes x 4 bf16 (8 B) = 512 B = exactly one 256-bf16 row.
// ---------------------------------------------------------------------------
__global__ __launch_bounds__(256) void gather_kernel(
    const short* __restrict__ h0h,
    const int* __restrict__ ends, const int* __restrict__ count,
    const int* __restrict__ csr_src, const float* __restrict__ csr_w,
    short* __restrict__ S)
{
    int gw = (blockIdx.x * 256 + threadIdx.x) >> 6;
    int lane = threadIdx.x & 63;
    if (gw >= N_REL * N_NODES) return;
    int r = gw / N_NODES;
    int node = gw - r * N_NODES;
    int end = ends[gw];
    int start = end - count[gw];
    float a0 = 0.f, a1 = 0.f, a2 = 0.f, a3 = 0.f;
    float den = 0.f;
    for (int p = start; p < end; ++p) {
        int s = csr_src[p];
        float wt = csr_w[p];
        short4 v = *(const short4*)(h0h + (size_t)s * HID + lane * 4);
        a0 = fmaf(wt, bf2f(v.x), a0);
        a1 = fmaf(wt, bf2f(v.y), a1);
        a2 = fmaf(wt, bf2f(v.z), a2);
        a3 = fmaf(wt, bf2f(v.w), a3);
        den += wt;
    }
    float inv = 1.0f / fmaxf(den, 1e-8f);
    short4 o;
    o.x = f2bf(a0 * inv);
    o.y = f2bf(a1 * inv);
    o.z = f2bf(a2 * inv);
    o.w = f2bf(a3 * inv);
    *(short4*)(S + (size_t)node * KR + r * HID + lane * 4) = o;
}

// ---------------------------------------------------------------------------
extern "C" void kernel_launch(void* const* d_in, const int* in_sizes, int n_in,
                              void* d_out, int out_size, void* d_ws, size_t ws_size,
                              hipStream_t stream) {
    const float* fa    = (const float*)d_in[0];
    const float* fb    = (const float*)d_in[1];
    const float* Wa    = (const float*)d_in[2];
    const float* Wb    = (const float*)d_in[3];
    const float* Wr    = (const float*)d_in[4];
    const float* gamma = (const float*)d_in[5];
    const float* beta  = (const float*)d_in[6];
    const float* ew    = (const float*)d_in[7];
    const int*   esrc  = (const int*)d_in[8];
    const int*   edst  = (const int*)d_in[9];
    float* out = (float*)d_out;

    char* ws = (char*)d_ws;
    size_t off = 0;
    short* h0h     = (short*)(ws + off); off += (size_t)N_NODES * HID * 2;   // 51.2 MB
    short* S       = (short*)(ws + off); off += (size_t)N_NODES * KR * 2;    // 153.6 MB
    short* WTp     = (short*)(ws + off); off += (size_t)256 * KP * 2;
    short* WTr     = (short*)(ws + off); off += (size_t)256 * KR * 2;
    int*   count   = (int*)  (ws + off); off += (size_t)NKEYS * 4;
    int*   offs    = (int*)  (ws + off); off += (size_t)NKEYS * 4;
    int*   bsum    = (int*)  (ws + off); off += 4096;
    int*   csr_src = (int*)  (ws + off); off += (size_t)N_EDGES * 4;
    float* csr_w   = (float*)(ws + off); off += (size_t)N_EDGES * 4;

    wprep_kernel<<<(256 * KP + 256 * KR) / 256, 256, 0, stream>>>(
        Wa, Wb, Wr, WTp, WTr);

    const int ngrid = (N_NODES + 127) / 128;   // 782
    proj_gemm<<<ngrid, 512, 0, stream>>>(fa, fb, WTp, h0h);

    // CSR build
    hipMemsetAsync(count, 0, (size_t)NKEYS * 4, stream);
    const int egrid = (N_EDGES + 255) / 256;
    hist_kernel<<<egrid, 256, 0, stream>>>(edst, count);
    scan1_kernel<<<NSCANBLK, 256, 0, stream>>>(count, offs, bsum);
    scan2_kernel<<<1, 256, 0, stream>>>(bsum);
    scan3_kernel<<<(NKEYS + 255) / 256, 256, 0, stream>>>(offs, bsum);
    fill_kernel<<<egrid, 256, 0, stream>>>(esrc, edst, ew, offs, csr_src, csr_w);

    gather_kernel<<<(N_REL * N_NODES * 64) / 256, 256, 0, stream>>>(
        h0h, offs, count, csr_src, csr_w, S);

    rel_gemm_ln<<<ngrid, 512, 0, stream>>>(S, WTr, h0h, gamma, beta, out);
}

// Round 7
// 527.427 us; speedup vs baseline: 12.3559x; 1.1323x over previous
//
#include <hip/hip_runtime.h>

#define N_NODES 100000
#define HID 256
#define N_EDGES 1500000
#define N_REL 3
#define E_PER_REL (N_EDGES / N_REL)
#define NKEYS (N_REL * N_NODES)
#define KP 640                 // proj K  (256 + 384)
#define KR 768                 // relation K (3 * 256)

#define SCAN_CHUNK 1024
#define NSCANBLK ((NKEYS + SCAN_CHUNK - 1) / SCAN_CHUNK)   // 293

typedef __attribute__((ext_vector_type(8))) short bf16x8;
typedef __attribute__((ext_vector_type(4))) float f32x4;

__device__ __forceinline__ short f2bf(float x) {  // RNE f32 -> bf16
    union { float f; unsigned u; } v; v.f = x;
    unsigned r = v.u + 0x7fffu + ((v.u >> 16) & 1u);
    return (short)(r >> 16);
}
__device__ __forceinline__ float bf2f(short h) {
    union { unsigned u; float f; } v;
    v.u = ((unsigned)(unsigned short)h) << 16;
    return v.f;
}
// slot swizzle: LDS row layout = [row][slot^xorf(row)], slot = 16B unit
__device__ __forceinline__ int xorf(int r) { return (r & 3) ^ ((r >> 2) & 3); }

// ---------------------------------------------------------------------------
// Weight prep: WTp[c][k] = bf16(0.5 * Wp[k][c])  (Wp = [Wa;Wb], k in [0,640))
//              WTr[c][k] = bf16(Wr[k>>8][k&255][c])          (k in [0,768))
// ---------------------------------------------------------------------------
__global__ __launch_bounds__(256) void wprep_kernel(
    const float* __restrict__ Wa, const float* __restrict__ Wb,
    const float* __restrict__ Wr,
    short* __restrict__ WTp, short* __restrict__ WTr)
{
    int idx = blockIdx.x * 256 + threadIdx.x;
    if (idx < 256 * KP) {
        int c = idx / KP, k = idx - c * KP;
        float v = (k < 256) ? Wa[k * HID + c] : Wb[(k - 256) * HID + c];
        WTp[idx] = f2bf(0.5f * v);
    } else {
        int j = idx - 256 * KP;
        if (j < 256 * KR) {
            int c = j / KR, k = j - c * KR;
            WTr[j] = f2bf(Wr[(k >> 8) * HID * HID + (k & 255) * HID + c]);
        }
    }
}

// ---------------------------------------------------------------------------
// proj GEMM: h0h[N,256] (bf16) = bf16( fa@(.5Wa) + fb@(.5Wb) ), row 0 zeroed.
// 512 threads, 8 waves (2 x 4), tile 128x256, wave tile 64x64, BK=32.
// Reg-staged + software-pipelined (prefetch k+1 issued before MFMA of k).
// ---------------------------------------------------------------------------
__global__ __launch_bounds__(512, 4) void proj_gemm(
    const float* __restrict__ fa, const float* __restrict__ fb,
    const short* __restrict__ WTp, short* __restrict__ h0h)
{
    __shared__ short smA[128 * 32];   // 8 KB
    __shared__ short smB[256 * 32];   // 16 KB
    const int tid = threadIdx.x;
    const int lane = tid & 63;
    const int w = tid >> 6;
    const int wr = w >> 2, wc = w & 3;
    const int brow = blockIdx.x * 128;

    f32x4 acc[4][4] = {};

    // A staging: thread t covers (row = t>>2, k-quad = t&3) -> 8 floats
    const int arow = tid >> 2;
    const int akq = tid & 3;
    int garow = brow + arow;
    if (garow >= N_NODES) garow = N_NODES - 1;
    const int aslot = akq ^ xorf(arow);
    // B staging: thread t covers (col = t>>1, k-half = t&1) -> 16 bf16
    const int bcol = tid >> 1;
    const int bkh = tid & 1;
    const int bs0 = (2 * bkh + 0) ^ xorf(bcol);
    const int bs1 = (2 * bkh + 1) ^ xorf(bcol);

    f32x4 pa0, pa1;
    bf16x8 pb0, pb1;
    auto loadA = [&](int k0) {
        const float* asrc; int astr, kk;
        if (k0 < 256) { asrc = fa; astr = 256; kk = k0; }
        else          { asrc = fb; astr = 384; kk = k0 - 256; }
        const float* ap = asrc + (size_t)garow * astr + kk + akq * 8;
        pa0 = *(const f32x4*)(ap + 0);
        pa1 = *(const f32x4*)(ap + 4);
    };
    auto loadB = [&](int k0) {
        const short* bp = WTp + (size_t)bcol * KP + k0 + bkh * 16;
        pb0 = *(const bf16x8*)(bp + 0);
        pb1 = *(const bf16x8*)(bp + 8);
    };

    loadA(0); loadB(0);
    for (int k0 = 0; k0 < KP; k0 += 32) {
        __syncthreads();   // previous iteration's LDS reads complete
        bf16x8 ha;
        ha[0] = f2bf(pa0.x); ha[1] = f2bf(pa0.y); ha[2] = f2bf(pa0.z); ha[3] = f2bf(pa0.w);
        ha[4] = f2bf(pa1.x); ha[5] = f2bf(pa1.y); ha[6] = f2bf(pa1.z); ha[7] = f2bf(pa1.w);
        *(bf16x8*)((char*)smA + arow * 64 + aslot * 16) = ha;
        *(bf16x8*)((char*)smB + bcol * 64 + bs0 * 16) = pb0;
        *(bf16x8*)((char*)smB + bcol * 64 + bs1 * 16) = pb1;
        __syncthreads();
        if (k0 + 32 < KP) { loadA(k0 + 32); loadB(k0 + 32); }  // prefetch

        bf16x8 afr[4], bfr[4];
        #pragma unroll
        for (int m = 0; m < 4; ++m) {
            int rt = wr * 64 + m * 16 + (lane & 15);
            int s = (lane >> 4) ^ xorf(rt);
            afr[m] = *(const bf16x8*)((const char*)smA + rt * 64 + s * 16);
        }
        #pragma unroll
        for (int n = 0; n < 4; ++n) {
            int ct = wc * 64 + n * 16 + (lane & 15);
            int s = (lane >> 4) ^ xorf(ct);
            bfr[n] = *(const bf16x8*)((const char*)smB + ct * 64 + s * 16);
        }
        #pragma unroll
        for (int m = 0; m < 4; ++m)
            #pragma unroll
            for (int n = 0; n < 4; ++n)
                acc[m][n] = __builtin_amdgcn_mfma_f32_16x16x32_bf16(
                    afr[m], bfr[n], acc[m][n], 0, 0, 0);
    }

    #pragma unroll
    for (int m = 0; m < 4; ++m) {
        #pragma unroll
        for (int j = 0; j < 4; ++j) {
            int row = brow + wr * 64 + m * 16 + ((lane >> 4) << 2) + j;
            if (row >= N_NODES) continue;
            #pragma unroll
            for (int n = 0; n < 4; ++n) {
                int col = wc * 64 + n * 16 + (lane & 15);
                short v = (row == 0) ? (short)0 : f2bf(acc[m][n][j]);
                h0h[(size_t)row * HID + col] = v;
            }
        }
    }
}

// ---------------------------------------------------------------------------
// rel GEMM + fused residual LayerNorm:
//   out[N,256] (f32) = LN( h0h + S@WTr^T ) * gamma + beta, row 0 zeroed.
// ---------------------------------------------------------------------------
__global__ __launch_bounds__(512, 4) void rel_gemm_ln(
    const short* __restrict__ S, const short* __restrict__ WTr,
    const short* __restrict__ h0h,
    const float* __restrict__ gamma, const float* __restrict__ beta,
    float* __restrict__ out)
{
    __shared__ short smA[128 * 32];     // 8 KB
    __shared__ short smB[256 * 32];     // 16 KB
    __shared__ float redS[128][4];      // 2 KB
    __shared__ float redS2[128][4];     // 2 KB
    __shared__ float smMean[128], smRs[128];   // 1 KB
    __shared__ float smG[256], smBt[256];      // 2 KB
    const int tid = threadIdx.x;
    const int lane = tid & 63;
    const int w = tid >> 6;
    const int wr = w >> 2, wc = w & 3;
    const int brow = blockIdx.x * 128;

    if (tid < 256) { smG[tid] = gamma[tid]; smBt[tid] = beta[tid]; }

    f32x4 acc[4][4] = {};

    const int arow = tid >> 2;
    const int akq = tid & 3;
    int garow = brow + arow;
    if (garow >= N_NODES) garow = N_NODES - 1;
    const int aslot = akq ^ xorf(arow);
    const int bcol = tid >> 1;
    const int bkh = tid & 1;
    const int bs0 = (2 * bkh + 0) ^ xorf(bcol);
    const int bs1 = (2 * bkh + 1) ^ xorf(bcol);

    bf16x8 pa, pb0, pb1;
    auto loadA = [&](int k0) {
        pa = *(const bf16x8*)(S + (size_t)garow * KR + k0 + akq * 8);
    };
    auto loadB = [&](int k0) {
        const short* bp = WTr + (size_t)bcol * KR + k0 + bkh * 16;
        pb0 = *(const bf16x8*)(bp + 0);
        pb1 = *(const bf16x8*)(bp + 8);
    };

    loadA(0); loadB(0);
    for (int k0 = 0; k0 < KR; k0 += 32) {
        __syncthreads();
        *(bf16x8*)((char*)smA + arow * 64 + aslot * 16) = pa;
        *(bf16x8*)((char*)smB + bcol * 64 + bs0 * 16) = pb0;
        *(bf16x8*)((char*)smB + bcol * 64 + bs1 * 16) = pb1;
        __syncthreads();
        if (k0 + 32 < KR) { loadA(k0 + 32); loadB(k0 + 32); }

        bf16x8 afr[4], bfr[4];
        #pragma unroll
        for (int m = 0; m < 4; ++m) {
            int rt = wr * 64 + m * 16 + (lane & 15);
            int s = (lane >> 4) ^ xorf(rt);
            afr[m] = *(const bf16x8*)((const char*)smA + rt * 64 + s * 16);
        }
        #pragma unroll
        for (int n = 0; n < 4; ++n) {
            int ct = wc * 64 + n * 16 + (lane & 15);
            int s = (lane >> 4) ^ xorf(ct);
            bfr[n] = *(const bf16x8*)((const char*)smB + ct * 64 + s * 16);
        }
        #pragma unroll
        for (int m = 0; m < 4; ++m)
            #pragma unroll
            for (int n = 0; n < 4; ++n)
                acc[m][n] = __builtin_amdgcn_mfma_f32_16x16x32_bf16(
                    afr[m], bfr[n], acc[m][n], 0, 0, 0);
    }

    // ---- epilogue: x = acc + h0 ; per-row mean/var ; LN ; write out ----
    #pragma unroll
    for (int m = 0; m < 4; ++m) {
        #pragma unroll
        for (int j = 0; j < 4; ++j) {
            int lrow = wr * 64 + m * 16 + ((lane >> 4) << 2) + j;
            int grow = brow + lrow;
            int crow = (grow < N_NODES) ? grow : 0;
            float s = 0.f, s2 = 0.f;
            #pragma unroll
            for (int n = 0; n < 4; ++n) {
                int col = wc * 64 + n * 16 + (lane & 15);
                float x = acc[m][n][j] + bf2f(h0h[(size_t)crow * HID + col]);
                acc[m][n][j] = x;
                s += x; s2 = fmaf(x, x, s2);
            }
            #pragma unroll
            for (int off = 1; off < 16; off <<= 1) {
                s += __shfl_xor(s, off, 64);
                s2 += __shfl_xor(s2, off, 64);
            }
            if ((lane & 15) == 0) { redS[lrow][wc] = s; redS2[lrow][wc] = s2; }
        }
    }
    __syncthreads();
    if (tid < 128) {
        float tot  = redS[tid][0] + redS[tid][1] + redS[tid][2] + redS[tid][3];
        float tot2 = redS2[tid][0] + redS2[tid][1] + redS2[tid][2] + redS2[tid][3];
        float mean = tot * (1.0f / HID);
        float var = tot2 * (1.0f / HID) - mean * mean;
        smMean[tid] = mean;
        smRs[tid] = rsqrtf(var + 1e-5f);
    }
    __syncthreads();
    #pragma unroll
    for (int m = 0; m < 4; ++m) {
        #pragma unroll
        for (int j = 0; j < 4; ++j) {
            int lrow = wr * 64 + m * 16 + ((lane >> 4) << 2) + j;
            int grow = brow + lrow;
            if (grow >= N_NODES) continue;
            float mean = smMean[lrow], rs = smRs[lrow];
            #pragma unroll
            for (int n = 0; n < 4; ++n) {
                int col = wc * 64 + n * 16 + (lane & 15);
                float y = (acc[m][n][j] - mean) * rs * smG[col] + smBt[col];
                out[(size_t)grow * HID + col] = (grow == 0) ? 0.f : y;
            }
        }
    }
}

// ---------------------------------------------------------------------------
// CSR build: histogram -> hierarchical exclusive scan -> bucket fill
// ---------------------------------------------------------------------------
__global__ __launch_bounds__(256) void hist_kernel(
    const int* __restrict__ dst, int* __restrict__ count)
{
    int i = blockIdx.x * 256 + threadIdx.x;
    if (i >= N_EDGES) return;
    int r = i / E_PER_REL;
    atomicAdd(&count[r * N_NODES + dst[i]], 1);
}

__global__ __launch_bounds__(256) void scan1_kernel(
    const int* __restrict__ count, int* __restrict__ offset,
    int* __restrict__ bsum)
{
    __shared__ int tmp[256];
    const int t = threadIdx.x;
    const int base = blockIdx.x * SCAN_CHUNK + t * 4;
    int v[4];
    #pragma unroll
    for (int j = 0; j < 4; ++j)
        v[j] = (base + j < NKEYS) ? count[base + j] : 0;
    int tsum = v[0] + v[1] + v[2] + v[3];
    tmp[t] = tsum;
    __syncthreads();
    #pragma unroll
    for (int off = 1; off < 256; off <<= 1) {
        int x = (t >= off) ? tmp[t - off] : 0;
        __syncthreads();
        tmp[t] += x;
        __syncthreads();
    }
    int run = tmp[t] - tsum;
    #pragma unroll
    for (int j = 0; j < 4; ++j) {
        if (base + j < NKEYS) offset[base + j] = run;
        run += v[j];
    }
    if (t == 0) bsum[blockIdx.x] = tmp[255];
}

__global__ __launch_bounds__(256) void scan2_kernel(int* __restrict__ bsum)
{
    __shared__ int tmp[256];
    const int t = threadIdx.x;
    int v0 = (2 * t     < NSCANBLK) ? bsum[2 * t]     : 0;
    int v1 = (2 * t + 1 < NSCANBLK) ? bsum[2 * t + 1] : 0;
    int psum = v0 + v1;
    tmp[t] = psum;
    __syncthreads();
    #pragma unroll
    for (int off = 1; off < 256; off <<= 1) {
        int x = (t >= off) ? tmp[t - off] : 0;
        __syncthreads();
        tmp[t] += x;
        __syncthreads();
    }
    int excl = tmp[t] - psum;
    if (2 * t     < NSCANBLK) bsum[2 * t]     = excl;
    if (2 * t + 1 < NSCANBLK) bsum[2 * t + 1] = excl + v0;
}

__global__ __launch_bounds__(256) void scan3_kernel(
    int* __restrict__ offset, const int* __restrict__ bsum)
{
    int i = blockIdx.x * 256 + threadIdx.x;
    if (i >= NKEYS) return;
    offset[i] += bsum[i / SCAN_CHUNK];
}

__global__ __launch_bounds__(256) void fill_kernel(
    const int* __restrict__ src, const int* __restrict__ dst,
    const float* __restrict__ w,
    int* __restrict__ offset, int* __restrict__ csr_src,
    float* __restrict__ csr_w)
{
    int i = blockIdx.x * 256 + threadIdx.x;
    if (i >= N_EDGES) return;
    int r = i / E_PER_REL;
    int key = r * N_NODES + dst[i];
    int pos = atomicAdd(&offset[key], 1);
    csr_src[pos] = src[i];
    csr_w[pos] = w[i];
}

// ---------------------------------------------------------------------------
// Gather: one wave per (relation, node).
// Lanes 0..deg-1 pre-load (src,w); loop shfl-broadcasts and issues 4
// independent row loads per chunk (tail predicated with w=0, dummy row =
// first edge's row -> cache hit). Serial fallback only for deg>64.
// ---------------------------------------------------------------------------
__global__ __launch_bounds__(256) void gather_kernel(
    const short* __restrict__ h0h,
    const int* __restrict__ ends, const int* __restrict__ count,
    const int* __restrict__ csr_src, const float* __restrict__ csr_w,
    short* __restrict__ S)
{
    int gw = (blockIdx.x * 256 + threadIdx.x) >> 6;
    int lane = threadIdx.x & 63;
    if (gw >= N_REL * N_NODES) return;
    int r = gw / N_NODES;
    int node = gw - r * N_NODES;
    int deg = count[gw];
    int end = ends[gw];
    int start = end - deg;
    const size_t colo = (size_t)lane * 4;

    float a0 = 0.f, a1 = 0.f, a2 = 0.f, a3 = 0.f;
    float den = 0.f;

    if (deg > 0) {
        int degc = (deg < 64) ? deg : 64;
        int myp = start + ((lane < degc) ? lane : 0);
        int msrc = csr_src[myp];
        float mw = (lane < degc) ? csr_w[myp] : 0.f;

        for (int p = 0; p < degc; p += 4) {
            #pragma unroll
            for (int j = 0; j < 4; ++j) {
                int q = p + j;
                bool ok = q < degc;
                int sj = __shfl(msrc, ok ? q : 0, 64);
                float wj = ok ? __shfl(mw, q, 64) : 0.f;
                short4 v = *(const short4*)(h0h + (size_t)sj * HID + colo);
                a0 = fmaf(wj, bf2f(v.x), a0);
                a1 = fmaf(wj, bf2f(v.y), a1);
                a2 = fmaf(wj, bf2f(v.z), a2);
                a3 = fmaf(wj, bf2f(v.w), a3);
                den += wj;
            }
        }
        // rare fallback for deg > 64
        for (int p = start + 64; p < end; ++p) {
            int s = csr_src[p];
            float wt = csr_w[p];
            short4 v = *(const short4*)(h0h + (size_t)s * HID + colo);
            a0 = fmaf(wt, bf2f(v.x), a0);
            a1 = fmaf(wt, bf2f(v.y), a1);
            a2 = fmaf(wt, bf2f(v.z), a2);
            a3 = fmaf(wt, bf2f(v.w), a3);
            den += wt;
        }
    }

    float inv = 1.0f / fmaxf(den, 1e-8f);
    short4 o;
    o.x = f2bf(a0 * inv);
    o.y = f2bf(a1 * inv);
    o.z = f2bf(a2 * inv);
    o.w = f2bf(a3 * inv);
    *(short4*)(S + (size_t)node * KR + r * HID + colo) = o;
}

// ---------------------------------------------------------------------------
extern "C" void kernel_launch(void* const* d_in, const int* in_sizes, int n_in,
                              void* d_out, int out_size, void* d_ws, size_t ws_size,
                              hipStream_t stream) {
    const float* fa    = (const float*)d_in[0];
    const float* fb    = (const float*)d_in[1];
    const float* Wa    = (const float*)d_in[2];
    const float* Wb    = (const float*)d_in[3];
    const float* Wr    = (const float*)d_in[4];
    const float* gamma = (const float*)d_in[5];
    const float* beta  = (const float*)d_in[6];
    const float* ew    = (const float*)d_in[7];
    const int*   esrc  = (const int*)d_in[8];
    const int*   edst  = (const int*)d_in[9];
    float* out = (float*)d_out;

    char* ws = (char*)d_ws;
    size_t off = 0;
    short* h0h     = (short*)(ws + off); off += (size_t)N_NODES * HID * 2;   // 51.2 MB
    short* S       = (short*)(ws + off); off += (size_t)N_NODES * KR * 2;    // 153.6 MB
    short* WTp     = (short*)(ws + off); off += (size_t)256 * KP * 2;
    short* WTr     = (short*)(ws + off); off += (size_t)256 * KR * 2;
    int*   count   = (int*)  (ws + off); off += (size_t)NKEYS * 4;
    int*   offs    = (int*)  (ws + off); off += (size_t)NKEYS * 4;
    int*   bsum    = (int*)  (ws + off); off += 4096;
    int*   csr_src = (int*)  (ws + off); off += (size_t)N_EDGES * 4;
    float* csr_w   = (float*)(ws + off); off += (size_t)N_EDGES * 4;

    wprep_kernel<<<(256 * KP + 256 * KR) / 256, 256, 0, stream>>>(
        Wa, Wb, Wr, WTp, WTr);

    const int ngrid = (N_NODES + 127) / 128;   // 782
    proj_gemm<<<ngrid, 512, 0, stream>>>(fa, fb, WTp, h0h);

    // CSR build
    hipMemsetAsync(count, 0, (size_t)NKEYS * 4, stream);
    const int egrid = (N_EDGES + 255) / 256;
    hist_kernel<<<egrid, 256, 0, stream>>>(edst, count);
    scan1_kernel<<<NSCANBLK, 256, 0, stream>>>(count, offs, bsum);
    scan2_kernel<<<1, 256, 0, stream>>>(bsum);
    scan3_kernel<<<(NKEYS + 255) / 256, 256, 0, stream>>>(offs, bsum);
    fill_kernel<<<egrid, 256, 0, stream>>>(esrc, edst, ew, offs, csr_src, csr_w);

    gather_kernel<<<(N_REL * N_NODES * 64) / 256, 256, 0, stream>>>(
        h0h, offs, count, csr_src, csr_w, S);

    rel_gemm_ln<<<ngrid, 512, 0, stream>>>(S, WTr, h0h, gamma, beta, out);
}